// Round 6
// baseline (178.631 us; speedup 1.0000x reference)
//
#include <hip/hip_runtime.h>

// Problem constants
#define NSPLIT  100
#define MTREE   20
#define MAXLEAF 64
#define EMB     32
#define NTREES  2000
#define BATCH   4096
#define OUTW    (NSPLIT*EMB)          // 3200

#define THREADS 512
#define CHUNKS  16                    // batch-chunks per split
#define BPC     (BATCH/CHUNKS)        // 256 batches per block
#define GROUPS  (THREADS/4)           // 128 groups of 4 lanes
#define TAB_F4  (MTREE*MAXLEAF*8)     // 10240 float4 per split table
#define LDS_BYTES (MTREE*MAXLEAF*64)  // 81920: whole table in bf16 (row=64B)

// v6: bf16 table in LDS -> half the LDS-port work (the measured bottleneck).
//  - f32 row (128B) -> bf16 row (64B): a 4-lane group reads a whole row, so
//    one ds_read_b128 wave-instr covers 16 gathers (vs 8 in f32). Port floor
//    ~20us -> ~10us chip-wide.
//  - 80 KiB LDS + 512 threads -> 2 blocks/CU: one block's staging/barrier
//    overlaps the other's gathers (v4 had zero overlap at 1 block/CU), and
//    the dispatch-tail quantum halves.
//  - Staging converts f32->bf16 with v_cvt_pk_bf16_f32 (RTNE): per-output
//    rounding error ~1e-3 on top of the 3.9e-3 compare floor; threshold 1.9e-2.
__device__ __forceinline__ unsigned int pk_bf16(float a, float b) {
    unsigned int r;
    asm("v_cvt_pk_bf16_f32 %0, %1, %2" : "=v"(r) : "v"(a), "v"(b));
    return r;
}

__global__ __launch_bounds__(THREADS, 4) void leaf2emb_v6(
    const int* __restrict__ leaves,     // [BATCH, NTREES]
    const float* __restrict__ embed,    // [NSPLIT, MTREE*MAXLEAF, EMB]
    float* __restrict__ out)            // [BATCH, OUTW]
{
    extern __shared__ unsigned int tabw[];  // row r = bytes [r*64, r*64+64)

    // XCD-chunked swizzle: 1600 blocks, XCD x works wkr in [x*200,(x+1)*200)
    // -> ~4 resident splits' tables (640KB) per XCD L2.
    const int bid = blockIdx.x;
    const int wkr = (bid & 7) * (NSPLIT * CHUNKS / 8) + (bid >> 3);
    const int s     = wkr >> 4;         // / CHUNKS
    const int chunk = wkr & 15;

    const int tid = threadIdx.x;
    const int l   = tid & 3;            // lane-in-group: dims [8l, 8l+8)
    const int g   = tid >> 2;           // group id = batch slot

    const float4* emb4 = (const float4*)embed + (size_t)s * TAB_F4;

    // ---- stage split table f32 -> bf16 LDS (RTNE) ----
    {
        uint2* tw = (uint2*)tabw;
#pragma unroll
        for (int k = 0; k < 20; ++k) {
            float4 v = emb4[tid + k * 512];
            tw[tid + k * 512] = make_uint2(pk_bf16(v.x, v.y), pk_bf16(v.z, v.w));
        }
    }

    // leaves for this group's 2 batches — issued pre-barrier, latency hides
    const int bA = chunk * BPC + g;
    const int bB = bA + GROUPS;
    const int* lvA = leaves + (size_t)bA * NTREES + s * MTREE;
    const int* lvB = leaves + (size_t)bB * NTREES + s * MTREE;
    const int4 A0 = *(const int4*)(lvA);      const int4 B0 = *(const int4*)(lvB);
    const int4 A1 = *(const int4*)(lvA + 4);  const int4 B1 = *(const int4*)(lvB + 4);
    const int4 A2 = *(const int4*)(lvA + 8);  const int4 B2 = *(const int4*)(lvB + 8);
    const int4 A3 = *(const int4*)(lvA + 12); const int4 B3 = *(const int4*)(lvB + 12);
    const int4 A4 = *(const int4*)(lvA + 16); const int4 B4 = *(const int4*)(lvB + 16);

    __syncthreads();

    const char* tb = (const char*)tabw + l * 16;

    float4 a0 = {0,0,0,0}, a1 = {0,0,0,0};   // batch A dims [8l..8l+4), [8l+4..8l+8)
    float4 c0 = {0,0,0,0}, c1 = {0,0,0,0};   // batch B

#define RD(T, LEAF) (*(const uint4*)(tb + (T)*4096 + ((LEAF) << 6)))
#define UNACC(P0, P1, V) { \
    P0.x += __uint_as_float((V).x << 16); P0.y += __uint_as_float((V).x & 0xffff0000u); \
    P0.z += __uint_as_float((V).y << 16); P0.w += __uint_as_float((V).y & 0xffff0000u); \
    P1.x += __uint_as_float((V).z << 16); P1.y += __uint_as_float((V).z & 0xffff0000u); \
    P1.z += __uint_as_float((V).w << 16); P1.w += __uint_as_float((V).w & 0xffff0000u); }

    // 8 independent ds_read_b128 in flight per 4-tree chunk (2 batches x 4)
#define CHUNK4(TB, LA, LB) { \
    uint4 va0 = RD((TB)+0, (LA).x), va1 = RD((TB)+1, (LA).y), \
          va2 = RD((TB)+2, (LA).z), va3 = RD((TB)+3, (LA).w); \
    uint4 vb0 = RD((TB)+0, (LB).x), vb1 = RD((TB)+1, (LB).y), \
          vb2 = RD((TB)+2, (LB).z), vb3 = RD((TB)+3, (LB).w); \
    UNACC(a0, a1, va0) UNACC(a0, a1, va1) UNACC(a0, a1, va2) UNACC(a0, a1, va3) \
    UNACC(c0, c1, vb0) UNACC(c0, c1, vb1) UNACC(c0, c1, vb2) UNACC(c0, c1, vb3) }

    CHUNK4(0,  A0, B0)
    CHUNK4(4,  A1, B1)
    CHUNK4(8,  A2, B2)
    CHUNK4(12, A3, B3)
    CHUNK4(16, A4, B4)

#undef RD
#undef UNACC
#undef CHUNK4

    // group's 4 lanes write 2 float4 each -> contiguous 128B per (b, s)
    float* oA = out + (size_t)bA * OUTW + s * EMB + l * 8;
    float* oB = out + (size_t)bB * OUTW + s * EMB + l * 8;
    *(float4*)(oA)     = a0;
    *(float4*)(oA + 4) = a1;
    *(float4*)(oB)     = c0;
    *(float4*)(oB + 4) = c1;
}

extern "C" void kernel_launch(void* const* d_in, const int* in_sizes, int n_in,
                              void* d_out, int out_size, void* d_ws, size_t ws_size,
                              hipStream_t stream) {
    const int* leaves  = (const int*)d_in[0];
    const float* embed = (const float*)d_in[1];
    float* out         = (float*)d_out;

    (void)hipFuncSetAttribute((const void*)leaf2emb_v6,
                              hipFuncAttributeMaxDynamicSharedMemorySize,
                              LDS_BYTES);

    dim3 grid(NSPLIT * CHUNKS);   // 1600
    dim3 block(THREADS);          // 512
    leaf2emb_v6<<<grid, block, LDS_BYTES, stream>>>(leaves, embed, out);
}

// Round 7
// 39.623 us; speedup vs baseline: 4.5083x; 4.5083x over previous
//
#include <hip/hip_runtime.h>

// Problem constants
#define NSPLIT  100
#define MTREE   20
#define MAXLEAF 64
#define EMB     32
#define NTREES  2000
#define BATCH   4096
#define OUTW    (NSPLIT*EMB)          // 3200

#define THREADS 1024
#define CHUNKS  16                    // batch-chunks per split
#define BPC     (BATCH/CHUNKS)        // 256 batches per block (1 per 4-lane group)
#define TAB_F4  (MTREE*MAXLEAF*8)     // 10240 float4 per split table
#define LDS_BYTES (MTREE*MAXLEAF*64)  // 81920: whole table bf16, row = 64B

// v7 = v6's bf16-LDS gather with the spills designed out.
//  - bf16 row = 64B -> one ds_read_b128 wave-instr covers 16 rows (2x v4's
//    f32 port efficiency). Whole table = 80 KiB -> 2 blocks/CU co-resident:
//    one block's staging overlaps the other's gathers.
//  - Per-thread live state <= ~50 VGPR by construction: 1 batch per group,
//    leaf int4 prefetched one chunk ahead (2 live), staging unroll 2,
//    4 gather uint4 in flight. v6 spilled ~35 regs/thread (506 MB scratch
//    writes) from 10-int4 leaf prefetch + 20-deep staging pipeline.
__device__ __forceinline__ unsigned int pk_bf16(float a, float b) {
    unsigned int r;
    asm("v_cvt_pk_bf16_f32 %0, %1, %2" : "=v"(r) : "v"(a), "v"(b));
    return r;
}

__global__ __launch_bounds__(THREADS, 2) void leaf2emb_v7(
    const int* __restrict__ leaves,     // [BATCH, NTREES]
    const float* __restrict__ embed,    // [NSPLIT, MTREE*MAXLEAF, EMB]
    float* __restrict__ out)            // [BATCH, OUTW]
{
    extern __shared__ unsigned int tabw[];   // row r = bytes [r*64, r*64+64)

    // XCD-chunked swizzle: 1600 = 8 x 200; XCD x stages ~12 consecutive
    // splits' tables -> staging reads L2-local.
    const int bid = blockIdx.x;
    const int wkr = (bid & 7) * (NSPLIT * CHUNKS / 8) + (bid >> 3);
    const int s     = wkr >> 4;         // / CHUNKS
    const int chunk = wkr & 15;

    const int tid = threadIdx.x;
    const int l   = tid & 3;            // lane-in-group: dims [8l, 8l+8)
    const int g   = tid >> 2;           // group id = batch slot (256 groups)

    // ---- stage split table f32 -> bf16 LDS (RTNE), 10 float4/thread ----
    {
        const float4* emb4 = (const float4*)embed + (size_t)s * TAB_F4;
        uint2* tw = (uint2*)tabw;
#pragma unroll 2
        for (int k = 0; k < 10; ++k) {
            float4 v = emb4[tid + k * 1024];
            tw[tid + k * 1024] = make_uint2(pk_bf16(v.x, v.y), pk_bf16(v.z, v.w));
        }
    }

    const int b = chunk * BPC + g;
    const int4* lv4 = (const int4*)(leaves + (size_t)b * NTREES + s * MTREE);
    int4 L = lv4[0];                    // chunk-0 leaves in flight w/ staging tail

    __syncthreads();

    const char* tb = (const char*)tabw + l * 16;
    float4 a0 = {0, 0, 0, 0}, a1 = {0, 0, 0, 0};   // dims [8l..8l+4), [8l+4..8l+8)

#define RD(BC, T, LEAF) (*(const uint4*)((BC) + (T)*4096 + ((LEAF) << 6)))
#define UNACC(V) { \
    a0.x += __uint_as_float((V).x << 16); a0.y += __uint_as_float((V).x & 0xffff0000u); \
    a0.z += __uint_as_float((V).y << 16); a0.w += __uint_as_float((V).y & 0xffff0000u); \
    a1.x += __uint_as_float((V).z << 16); a1.y += __uint_as_float((V).z & 0xffff0000u); \
    a1.z += __uint_as_float((V).w << 16); a1.w += __uint_as_float((V).w & 0xffff0000u); }

    // 4 trees per chunk, 4 uint4 in flight; ds offset imm stays < 16K via
    // per-chunk base pointer.
#define CHUNK4(C) { \
        const char* bc = tb + (C) * 16384; \
        uint4 v0 = RD(bc, 0, L.x); \
        uint4 v1 = RD(bc, 1, L.y); \
        uint4 v2 = RD(bc, 2, L.z); \
        uint4 v3 = RD(bc, 3, L.w); \
        UNACC(v0) UNACC(v1) UNACC(v2) UNACC(v3) }

    int4 Ln;
    Ln = lv4[1]; CHUNK4(0) L = Ln;
    Ln = lv4[2]; CHUNK4(1) L = Ln;
    Ln = lv4[3]; CHUNK4(2) L = Ln;
    Ln = lv4[4]; CHUNK4(3) L = Ln;
    CHUNK4(4)

#undef RD
#undef UNACC
#undef CHUNK4

    // group's 4 lanes write 2 float4 each -> contiguous 128B per (b, s)
    float* ob = out + (size_t)b * OUTW + s * EMB + l * 8;
    *(float4*)(ob)     = a0;
    *(float4*)(ob + 4) = a1;
}

extern "C" void kernel_launch(void* const* d_in, const int* in_sizes, int n_in,
                              void* d_out, int out_size, void* d_ws, size_t ws_size,
                              hipStream_t stream) {
    const int* leaves  = (const int*)d_in[0];
    const float* embed = (const float*)d_in[1];
    float* out         = (float*)d_out;

    (void)hipFuncSetAttribute((const void*)leaf2emb_v7,
                              hipFuncAttributeMaxDynamicSharedMemorySize,
                              LDS_BYTES);

    dim3 grid(NSPLIT * CHUNKS);   // 1600
    dim3 block(THREADS);          // 1024
    leaf2emb_v7<<<grid, block, LDS_BYTES, stream>>>(leaves, embed, out);
}